// Round 4
// baseline (1419.376 us; speedup 1.0000x reference)
//
#include <hip/hip_runtime.h>

// SparseConvTransposeBlock, round 4: zero global float atomics.
//
// R1/R3 evidence: atomic scatter is BYTE-bound at the RMW point (R3's 4x
// segment coalescing changed nothing: identical 540MB WRITE, 1.8TB/s,
// 445us). So: CSR-sort pairs by output row (int atomics only, ~11MB ws),
// then each block OWNS a 64-row output tile in LDS, gathers its pairs
// (contiguous in perm), counting-sorts them by k, runs bf16 MFMA per k,
// accumulates via LDS atomics, and writes out ONCE (plain coalesced
// stores) with BN stats fused. Global float atomics: zero.
//
// Bias cancels in training-mode BN: y = (acc - mean_acc)*rsqrt(var)*g + b.

#define C_DIM 64
#define R_TILE 64       // output rows per block (LDS tile)
#define OT_STRIDE 68    // fp32 out-tile row stride (64 + 4 pad)
#define LIST_CAP 1536   // pair records per chunk = 6 * 256
#define LDS_STRIDE 72   // fallback kernel: bf16 Wt row stride

typedef __bf16 bf16_t;
typedef bf16_t bf16x8 __attribute__((ext_vector_type(8)));
typedef float floatx4 __attribute__((ext_vector_type(4)));

// ---------------------------------------------------------------- CSR build
__global__ __launch_bounds__(256)
void k_hist(const int* __restrict__ pout, int* __restrict__ counts, int M)
{
    int j = blockIdx.x * 256 + threadIdx.x;
    if (j < M) atomicAdd(&counts[pout[j]], 1);
}

__global__ __launch_bounds__(256)
void k_scan_a(const int* __restrict__ counts, int* __restrict__ partials, int n)
{
    __shared__ int ls[256];
    int tid = threadIdx.x;
    int base = blockIdx.x * 1024 + tid * 4;
    int s = 0;
    #pragma unroll
    for (int j = 0; j < 4; ++j)
        if (base + j < n) s += counts[base + j];
    ls[tid] = s;
    __syncthreads();
    for (int off = 128; off > 0; off >>= 1) {
        if (tid < off) ls[tid] += ls[tid + off];
        __syncthreads();
    }
    if (tid == 0) partials[blockIdx.x] = ls[0];
}

__global__ __launch_bounds__(1024)
void k_scan_b(int* __restrict__ partials, int nb)
{
    __shared__ int ls[1024];
    int tid = threadIdx.x;
    ls[tid] = (tid < nb) ? partials[tid] : 0;
    __syncthreads();
    if (tid == 0) {
        int run = 0;
        for (int i = 0; i < nb; ++i) { int t = ls[i]; ls[i] = run; run += t; }
    }
    __syncthreads();
    if (tid < nb) partials[tid] = ls[tid];
}

// counts -> row_start (exclusive scan) AND cursor := row_start.
__global__ __launch_bounds__(256)
void k_scan_c(int* __restrict__ cursor, int* __restrict__ offsets,
              const int* __restrict__ partials, int n, int M)
{
    __shared__ int ls[256];
    int tid = threadIdx.x;
    int base = blockIdx.x * 1024 + tid * 4;
    int v[4];
    #pragma unroll
    for (int j = 0; j < 4; ++j)
        v[j] = (base + j < n) ? cursor[base + j] : 0;
    int tsum = v[0] + v[1] + v[2] + v[3];
    ls[tid] = tsum;
    __syncthreads();
    for (int off = 1; off < 256; off <<= 1) {
        int t = (tid >= off) ? ls[tid - off] : 0;
        __syncthreads();
        ls[tid] += t;
        __syncthreads();
    }
    int run = partials[blockIdx.x] + ls[tid] - tsum;
    #pragma unroll
    for (int j = 0; j < 4; ++j) {
        if (base + j < n) {
            offsets[base + j] = run;
            cursor[base + j]  = run;
            run += v[j];
        }
    }
    if (blockIdx.x == 0 && tid == 0) offsets[n] = M;
}

__global__ __launch_bounds__(256)
void k_scatter_perm(const int* __restrict__ pout, int* __restrict__ cursor,
                    int* __restrict__ perm, int M)
{
    int j = blockIdx.x * 256 + threadIdx.x;
    if (j < M) {
        int slot = atomicAdd(&cursor[pout[j]], 1);
        perm[slot] = j;
    }
}

// W[k][kk][n] (f32) -> wbt[k][n][kk] (bf16), for direct B-fragment loads.
__global__ __launch_bounds__(256)
void k_wprep(const float* __restrict__ w, bf16_t* __restrict__ wbt, int total)
{
    int i = blockIdx.x * 256 + threadIdx.x;
    if (i < total) {
        int k  = i >> 12;         // / 4096
        int r  = i & 4095;
        int kk = r >> 6;
        int n  = r & 63;
        wbt[((size_t)k * 64 + n) * 64 + kk] = (bf16_t)w[i];
    }
}

// --------------------- main: per-output-tile gather + MFMA + LDS accumulate
__global__ __launch_bounds__(256)
void k_tile_acc(const float* __restrict__ features,
                const int* __restrict__ pairs_in,
                const int* __restrict__ pairs_out,
                const int* __restrict__ row_start,
                const int* __restrict__ perm,
                const bf16_t* __restrict__ wbt,
                float* __restrict__ out,
                float* __restrict__ sums,
                int n_out, int P, int K3)
{
    __shared__ float        ot[(R_TILE + 1) * OT_STRIDE]; // +1 trash row for pad lanes
    __shared__ unsigned int list[LIST_CAP];
    __shared__ int hist[32], bstart[32], cur[32];
    __shared__ float red[128];

    const int tid  = threadIdx.x;
    const int wave = tid >> 6;
    const int lane = tid & 63;
    const int quad = lane >> 4;
    const int col  = lane & 15;

    const int r0   = blockIdx.x * R_TILE;
    const int rend = min(r0 + R_TILE, n_out);

    for (int i = tid; i < (R_TILE + 1) * OT_STRIDE; i += 256) ot[i] = 0.f;

    const int tbeg = row_start[r0];
    const int tend = row_start[rend];

    for (int cbeg = tbeg; cbeg < tend; cbeg += LIST_CAP) {
        const int ccnt = min(LIST_CAP, tend - cbeg);

        __syncthreads();                   // covers ot-init / prior chunk reads
        if (tid < 32) hist[tid] = 0;
        __syncthreads();

        // Stage this chunk's records in registers; histogram k.
        unsigned int pk[6];
        int kk[6];
        #pragma unroll
        for (int t = 0; t < 6; ++t) {
            int i = t * 256 + tid;
            kk[t] = -1;
            if (i < ccnt) {
                int j   = perm[cbeg + i];
                int k   = (int)((unsigned)j / (unsigned)P);
                int in  = pairs_in[j];
                int row = pairs_out[j];
                pk[t] = ((unsigned)in << 6) | (unsigned)(row - r0);
                kk[t] = k;
                atomicAdd(&hist[k], 1);
            }
        }
        __syncthreads();
        if (tid == 0) {
            int run = 0;
            for (int k = 0; k < K3; ++k) { bstart[k] = run; cur[k] = run; run += hist[k]; }
        }
        __syncthreads();
        #pragma unroll
        for (int t = 0; t < 6; ++t) {
            if (kk[t] >= 0) {
                int pos = atomicAdd(&cur[kk[t]], 1);
                list[pos] = pk[t];
            }
        }
        __syncthreads();

        // Per-k MFMA over the bucketed pair list.
        for (int kb = 0; kb < K3; ++kb) {
            const int cnt = hist[kb];
            if (cnt == 0) continue;

            const bf16_t* wb = wbt + (size_t)kb * C_DIM * C_DIM;
            bf16x8 bfrag[2][4];
            #pragma unroll
            for (int ks = 0; ks < 2; ++ks)
                #pragma unroll
                for (int nt = 0; nt < 4; ++nt)
                    bfrag[ks][nt] =
                        *(const bf16x8*)&wb[(col + 16 * nt) * C_DIM + quad * 8 + 32 * ks];

            const int bs  = bstart[kb];
            const int ngr = (cnt + 15) >> 4;

            for (int g = wave; g < ngr; g += 4) {
                int idx = g * 16 + col;
                unsigned int val = list[bs + min(idx, cnt - 1)];
                int in_idx = (int)(val >> 6);

                const float* src = features + (size_t)in_idx * C_DIM + quad * 8;
                float4 f0 = *(const float4*)(src);
                float4 f1 = *(const float4*)(src + 4);
                float4 f2 = *(const float4*)(src + 32);
                float4 f3 = *(const float4*)(src + 36);

                bf16x8 a0, a1;
                a0[0] = (bf16_t)f0.x; a0[1] = (bf16_t)f0.y; a0[2] = (bf16_t)f0.z; a0[3] = (bf16_t)f0.w;
                a0[4] = (bf16_t)f1.x; a0[5] = (bf16_t)f1.y; a0[6] = (bf16_t)f1.z; a0[7] = (bf16_t)f1.w;
                a1[0] = (bf16_t)f2.x; a1[1] = (bf16_t)f2.y; a1[2] = (bf16_t)f2.z; a1[3] = (bf16_t)f2.w;
                a1[4] = (bf16_t)f3.x; a1[5] = (bf16_t)f3.y; a1[6] = (bf16_t)f3.z; a1[7] = (bf16_t)f3.w;

                floatx4 acc0 = {0.f, 0.f, 0.f, 0.f};
                floatx4 acc1 = {0.f, 0.f, 0.f, 0.f};
                floatx4 acc2 = {0.f, 0.f, 0.f, 0.f};
                floatx4 acc3 = {0.f, 0.f, 0.f, 0.f};

                acc0 = __builtin_amdgcn_mfma_f32_16x16x32_bf16(a0, bfrag[0][0], acc0, 0, 0, 0);
                acc0 = __builtin_amdgcn_mfma_f32_16x16x32_bf16(a1, bfrag[1][0], acc0, 0, 0, 0);
                acc1 = __builtin_amdgcn_mfma_f32_16x16x32_bf16(a0, bfrag[0][1], acc1, 0, 0, 0);
                acc1 = __builtin_amdgcn_mfma_f32_16x16x32_bf16(a1, bfrag[1][1], acc1, 0, 0, 0);
                acc2 = __builtin_amdgcn_mfma_f32_16x16x32_bf16(a0, bfrag[0][2], acc2, 0, 0, 0);
                acc2 = __builtin_amdgcn_mfma_f32_16x16x32_bf16(a1, bfrag[1][2], acc2, 0, 0, 0);
                acc3 = __builtin_amdgcn_mfma_f32_16x16x32_bf16(a0, bfrag[0][3], acc3, 0, 0, 0);
                acc3 = __builtin_amdgcn_mfma_f32_16x16x32_bf16(a1, bfrag[1][3], acc3, 0, 0, 0);

                // Accumulate into the LDS out tile. C/D: row m=quad*4+r, ch col+16j.
                // Pad lanes (idx>=cnt) land in trash row R_TILE.
                #pragma unroll
                for (int r = 0; r < 4; ++r) {
                    int m = quad * 4 + r;
                    unsigned int vm = __shfl(val, m);
                    int lrow = (g * 16 + m < cnt) ? (int)(vm & 63) : R_TILE;
                    float* dst = &ot[lrow * OT_STRIDE + col];
                    atomicAdd(dst +  0, acc0[r]);
                    atomicAdd(dst + 16, acc1[r]);
                    atomicAdd(dst + 32, acc2[r]);
                    atomicAdd(dst + 48, acc3[r]);
                }
            }
        }
    }
    __syncthreads();

    // Write tile out once (coalesced) + fused BN partial sums.
    float s[4]  = {0.f, 0.f, 0.f, 0.f};
    float s2[4] = {0.f, 0.f, 0.f, 0.f};
    for (int i = tid; i < R_TILE * 16; i += 256) {   // 16 float4 per row
        int rr = i >> 4, c4 = i & 15;                // c4 constant per thread
        int row = r0 + rr;
        if (row < n_out) {
            float4 v = *(const float4*)&ot[rr * OT_STRIDE + c4 * 4];
            *(float4*)&out[(size_t)row * C_DIM + c4 * 4] = v;
            s[0] += v.x; s2[0] += v.x * v.x;
            s[1] += v.y; s2[1] += v.y * v.y;
            s[2] += v.z; s2[2] += v.z * v.z;
            s[3] += v.w; s2[3] += v.w * v.w;
        }
    }
    if (tid < 128) red[tid] = 0.f;
    __syncthreads();
    {
        int c4 = tid & 15;
        #pragma unroll
        for (int j = 0; j < 4; ++j) {
            atomicAdd(&red[c4 * 4 + j], s[j]);
            atomicAdd(&red[64 + c4 * 4 + j], s2[j]);
        }
    }
    __syncthreads();
    if (tid < 128) atomicAdd(&sums[tid], red[tid]);
}

// --------------------------------------------------- BN normalize + ReLU
__global__ __launch_bounds__(256)
void k3_bn_relu(float* __restrict__ out, const float* __restrict__ sums,
                const float* __restrict__ gamma, const float* __restrict__ beta,
                int n_rows)
{
    int tid = blockIdx.x * 256 + threadIdx.x;
    int ch0 = (tid * 4) & 63;
    float inv_n = 1.0f / (float)n_rows;

    float sc[4], sh[4];
    #pragma unroll
    for (int j = 0; j < 4; ++j) {
        int ch    = ch0 + j;
        float m   = sums[ch] * inv_n;
        float var = sums[64 + ch] * inv_n - m * m;
        float inv = rsqrtf(var + 1e-5f);
        float g   = gamma[ch] * inv;
        sc[j] = g;
        sh[j] = beta[ch] - m * g;
    }

    size_t total = (size_t)n_rows * C_DIM / 4;
    for (size_t i = tid; i < total; i += (size_t)gridDim.x * 256) {
        float4 v = ((const float4*)out)[i];
        v.x = fmaxf(v.x * sc[0] + sh[0], 0.f);
        v.y = fmaxf(v.y * sc[1] + sh[1], 0.f);
        v.z = fmaxf(v.z * sc[2] + sh[2], 0.f);
        v.w = fmaxf(v.w * sc[3] + sh[3], 0.f);
        ((float4*)out)[i] = v;
    }
}

// ===================== fallback (R1 atomic path, known-good) ================
__global__ __launch_bounds__(256)
void k1_scatter_gemm(const float* __restrict__ features,
                     const float* __restrict__ weight,
                     const int* __restrict__ pairs_in,
                     const int* __restrict__ pairs_out,
                     float* __restrict__ out,
                     int P, int rows_per_block)
{
    __shared__ bf16_t Wt[C_DIM * LDS_STRIDE];
    const int k   = blockIdx.y;
    const int tid = threadIdx.x;
    const float* Wk = weight + (size_t)k * C_DIM * C_DIM;
    for (int i = tid; i < C_DIM * C_DIM; i += 256) {
        int c = i >> 6, d = i & 63;
        Wt[d * LDS_STRIDE + c] = (bf16_t)Wk[i];
    }
    __syncthreads();
    const int wave = tid >> 6, lane = tid & 63, quad = lane >> 4, col = lane & 15;
    bf16x8 bfrag[2][4];
    #pragma unroll
    for (int ks = 0; ks < 2; ++ks)
        #pragma unroll
        for (int nt = 0; nt < 4; ++nt)
            bfrag[ks][nt] =
                *(const bf16x8*)&Wt[(col + 16 * nt) * LDS_STRIDE + quad * 8 + 32 * ks];
    const int* __restrict__ pin  = pairs_in  + (size_t)k * P;
    const int* __restrict__ pout = pairs_out + (size_t)k * P;
    const int p0   = blockIdx.x * rows_per_block;
    const int pend = min(p0 + rows_per_block, P);
    for (int base = p0 + wave * 16; base < pend; base += 64) {
        int prow    = base + col;
        int clamped = (prow < pend) ? prow : (pend - 1);
        int in_idx  = pin[clamped];
        int out_idx = pout[clamped];
        const float* src = features + (size_t)in_idx * C_DIM + quad * 8;
        float4 f0 = *(const float4*)(src);
        float4 f1 = *(const float4*)(src + 4);
        float4 f2 = *(const float4*)(src + 32);
        float4 f3 = *(const float4*)(src + 36);
        bf16x8 a0, a1;
        a0[0] = (bf16_t)f0.x; a0[1] = (bf16_t)f0.y; a0[2] = (bf16_t)f0.z; a0[3] = (bf16_t)f0.w;
        a0[4] = (bf16_t)f1.x; a0[5] = (bf16_t)f1.y; a0[6] = (bf16_t)f1.z; a0[7] = (bf16_t)f1.w;
        a1[0] = (bf16_t)f2.x; a1[1] = (bf16_t)f2.y; a1[2] = (bf16_t)f2.z; a1[3] = (bf16_t)f2.w;
        a1[4] = (bf16_t)f3.x; a1[5] = (bf16_t)f3.y; a1[6] = (bf16_t)f3.z; a1[7] = (bf16_t)f3.w;
        floatx4 acc0 = {0.f,0.f,0.f,0.f}, acc1 = {0.f,0.f,0.f,0.f};
        floatx4 acc2 = {0.f,0.f,0.f,0.f}, acc3 = {0.f,0.f,0.f,0.f};
        acc0 = __builtin_amdgcn_mfma_f32_16x16x32_bf16(a0, bfrag[0][0], acc0, 0, 0, 0);
        acc0 = __builtin_amdgcn_mfma_f32_16x16x32_bf16(a1, bfrag[1][0], acc0, 0, 0, 0);
        acc1 = __builtin_amdgcn_mfma_f32_16x16x32_bf16(a0, bfrag[0][1], acc1, 0, 0, 0);
        acc1 = __builtin_amdgcn_mfma_f32_16x16x32_bf16(a1, bfrag[1][1], acc1, 0, 0, 0);
        acc2 = __builtin_amdgcn_mfma_f32_16x16x32_bf16(a0, bfrag[0][2], acc2, 0, 0, 0);
        acc2 = __builtin_amdgcn_mfma_f32_16x16x32_bf16(a1, bfrag[1][2], acc2, 0, 0, 0);
        acc3 = __builtin_amdgcn_mfma_f32_16x16x32_bf16(a0, bfrag[0][3], acc3, 0, 0, 0);
        acc3 = __builtin_amdgcn_mfma_f32_16x16x32_bf16(a1, bfrag[1][3], acc3, 0, 0, 0);
        #pragma unroll
        for (int r = 0; r < 4; ++r) {
            int m = quad * 4 + r;
            int g = __shfl(out_idx, m);
            if (base + m < pend) {
                float* dst = out + (size_t)g * C_DIM + col;
                unsafeAtomicAdd(dst +  0, acc0[r]);
                unsafeAtomicAdd(dst + 16, acc1[r]);
                unsafeAtomicAdd(dst + 32, acc2[r]);
                unsafeAtomicAdd(dst + 48, acc3[r]);
            }
        }
    }
}

__global__ __launch_bounds__(256)
void k2_stats(const float* __restrict__ acc, float* __restrict__ sums, int n_rows)
{
    int tid = threadIdx.x;
    int ch  = tid & 63;
    int sub = tid >> 6;
    float s = 0.f, s2 = 0.f;
    for (int r = blockIdx.x * 4 + sub; r < n_rows; r += gridDim.x * 4) {
        float v = acc[(size_t)r * C_DIM + ch];
        s  += v;
        s2 += v * v;
    }
    __shared__ float red[256];
    red[tid] = s;
    __syncthreads();
    if (tid < 64) {
        float t = red[tid] + red[tid + 64] + red[tid + 128] + red[tid + 192];
        atomicAdd(&sums[ch], t);
    }
    __syncthreads();
    red[tid] = s2;
    __syncthreads();
    if (tid < 64) {
        float t = red[tid] + red[tid + 64] + red[tid + 128] + red[tid + 192];
        atomicAdd(&sums[64 + ch], t);
    }
}

// ============================================================================
extern "C" void kernel_launch(void* const* d_in, const int* in_sizes, int n_in,
                              void* d_out, int out_size, void* d_ws, size_t ws_size,
                              hipStream_t stream)
{
    const float* features  = (const float*)d_in[0];
    const float* weight    = (const float*)d_in[1];
    // d_in[2] = bias (cancels in training-mode BN)
    const float* gamma     = (const float*)d_in[3];
    const float* beta      = (const float*)d_in[4];
    const int*   pairs_in  = (const int*)d_in[5];
    const int*   pairs_out = (const int*)d_in[6];

    const int n_out = out_size / C_DIM;
    const int K3    = in_sizes[1] / (C_DIM * C_DIM);
    const int P     = in_sizes[5] / K3;
    const int M     = in_sizes[5];
    const int nb    = (n_out + 1023) / 1024;

    float* out = (float*)d_out;

    // ws layout (bytes)
    size_t off_sums  = 0;                              // 128 f32
    size_t off_rs    = 512;                            // row_start: n_out+1 ints
    size_t off_cur   = off_rs  + (size_t)(n_out + 1) * 4;   // cursor: n_out ints
    size_t off_part  = off_cur + (size_t)n_out * 4;         // partials: nb ints
    size_t off_wbt   = (off_part + (size_t)nb * 4 + 255) & ~(size_t)255;
    size_t off_perm  = (off_wbt + (size_t)K3 * C_DIM * C_DIM * 2 + 255) & ~(size_t)255;
    size_t need      = off_perm + (size_t)M * 4;

    float*  sums      = (float*)((char*)d_ws + off_sums);
    int*    row_start = (int*)((char*)d_ws + off_rs);
    int*    cursor    = (int*)((char*)d_ws + off_cur);
    int*    partials  = (int*)((char*)d_ws + off_part);
    bf16_t* wbt       = (bf16_t*)((char*)d_ws + off_wbt);
    int*    perm      = (int*)((char*)d_ws + off_perm);

    if (ws_size >= need && nb <= 1024 && K3 <= 32) {
        hipMemsetAsync(sums, 0, 512, stream);
        hipMemsetAsync(cursor, 0, (size_t)n_out * 4, stream);

        k_hist<<<(M + 255) / 256, 256, 0, stream>>>(pairs_out, cursor, M);
        k_scan_a<<<nb, 256, 0, stream>>>(cursor, partials, n_out);
        k_scan_b<<<1, 1024, 0, stream>>>(partials, nb);
        k_scan_c<<<nb, 256, 0, stream>>>(cursor, row_start, partials, n_out, M);
        k_scatter_perm<<<(M + 255) / 256, 256, 0, stream>>>(pairs_out, cursor, perm, M);
        k_wprep<<<(K3 * 4096 + 255) / 256, 256, 0, stream>>>(weight, wbt, K3 * 4096);

        int ntiles = (n_out + R_TILE - 1) / R_TILE;
        k_tile_acc<<<ntiles, 256, 0, stream>>>(features, pairs_in, pairs_out,
                                               row_start, perm, wbt,
                                               out, sums, n_out, P, K3);

        k3_bn_relu<<<dim3(1024), 256, 0, stream>>>(out, sums, gamma, beta, n_out);
    } else {
        // fallback: R1 atomic-scatter path (proven)
        hipMemsetAsync(d_out, 0, (size_t)out_size * sizeof(float), stream);
        hipMemsetAsync(d_ws, 0, 512, stream);

        const int rows_per_block = 512;
        dim3 g1((P + rows_per_block - 1) / rows_per_block, K3);
        k1_scatter_gemm<<<g1, 256, 0, stream>>>(features, weight, pairs_in,
                                                pairs_out, out, P, rows_per_block);
        k2_stats<<<dim3(1024), 256, 0, stream>>>(out, sums, n_out);
        k3_bn_relu<<<dim3(1024), 256, 0, stream>>>(out, sums, gamma, beta, n_out);
    }
}

// Round 5
// 1313.951 us; speedup vs baseline: 1.0802x; 1.0802x over previous
//
#include <hip/hip_runtime.h>

// SparseConvTransposeBlock, round 5: pre-sorted, barrier-free tile kernel.
//
// R4: ownership scheme fixed traffic (WRITE 540->51.5MB) but in-kernel
// bucketing serialized everything (1048us, all pipes idle). R5 moves the
// sort into the CSR build: pairs sorted by key=(row/64)*32+k, each bucket
// padded to a multiple of 16 with 0xFFFFFFFF sentinels, records pre-packed
// as k<<23|in<<6|lrow. Main kernel: waves stream contiguous 16-entry
// single-k groups -> coalesced packed read, feature gather, 8 MFMAs,
// LDS-atomic accumulate, B-frags reloaded only on k change. No barriers in
// the steady loop; 17.7KB LDS -> 8 blocks/CU.
//
// Bias cancels in training-mode BN: y = (acc - mean_acc)*rsqrt(var)*g + b.

#define C_DIM 64
#define R_TILE 64
#define OT_STRIDE 68    // fp32 out-tile row stride (64 + 4 pad)
#define KSLOT 32        // bucket keys per tile (k < 32)
#define LDS_STRIDE 72   // fallback kernel: bf16 Wt row stride

typedef __bf16 bf16_t;
typedef bf16_t bf16x8 __attribute__((ext_vector_type(8)));
typedef float floatx4 __attribute__((ext_vector_type(4)));

// ------------------------------------------------------------- bucket build
// grid: (ceil(P/256), K3). Coalesced pair reads, no integer division.
__global__ __launch_bounds__(256)
void k_hist2(const int* __restrict__ pairs_out, int* __restrict__ counts, int P)
{
    int p = blockIdx.x * 256 + threadIdx.x;
    if (p < P) {
        int row = pairs_out[(size_t)blockIdx.y * P + p];
        atomicAdd(&counts[(row >> 6) * KSLOT + blockIdx.y], 1);
    }
}

// padded per-1024 block sums
__global__ __launch_bounds__(256)
void k_scan_a(const int* __restrict__ counts, int* __restrict__ partials, int n)
{
    __shared__ int ls[256];
    int tid = threadIdx.x;
    int base = blockIdx.x * 1024 + tid * 4;
    int s = 0;
    #pragma unroll
    for (int j = 0; j < 4; ++j)
        if (base + j < n) s += (counts[base + j] + 15) & ~15;
    ls[tid] = s;
    __syncthreads();
    for (int off = 128; off > 0; off >>= 1) {
        if (tid < off) ls[tid] += ls[tid + off];
        __syncthreads();
    }
    if (tid == 0) partials[blockIdx.x] = ls[0];
}

__global__ __launch_bounds__(1024)
void k_scan_b(int* __restrict__ partials, int nb)
{
    __shared__ int ls[1024];
    int tid = threadIdx.x;
    ls[tid] = (tid < nb) ? partials[tid] : 0;
    __syncthreads();
    if (tid == 0) {
        int run = 0;
        for (int i = 0; i < nb; ++i) { int t = ls[i]; ls[i] = run; run += t; }
    }
    __syncthreads();
    if (tid < nb) partials[tid] = ls[tid];
}

// counts(cursor) -> padded exclusive scan; bucket_start & cursor := start.
__global__ __launch_bounds__(256)
void k_scan_c(int* __restrict__ cursor, int* __restrict__ bstart,
              const int* __restrict__ partials, int n)
{
    __shared__ int ls[256];
    int tid = threadIdx.x;
    int base = blockIdx.x * 1024 + tid * 4;
    int v[4];
    #pragma unroll
    for (int j = 0; j < 4; ++j)
        v[j] = (base + j < n) ? ((cursor[base + j] + 15) & ~15) : 0;
    int tsum = v[0] + v[1] + v[2] + v[3];
    ls[tid] = tsum;
    __syncthreads();
    for (int off = 1; off < 256; off <<= 1) {
        int t = (tid >= off) ? ls[tid - off] : 0;
        __syncthreads();
        ls[tid] += t;
        __syncthreads();
    }
    int run = partials[blockIdx.x] + ls[tid] - tsum;
    #pragma unroll
    for (int j = 0; j < 4; ++j) {
        if (base + j < n) {
            bstart[base + j] = run;
            cursor[base + j] = run;
            run += v[j];
        }
    }
    if (base <= n - 1 && n - 1 < base + 4) bstart[n] = run;
}

// grid: (ceil(P/256), K3). Pack record and scatter to its bucket slot.
__global__ __launch_bounds__(256)
void k_scatter2(const int* __restrict__ pairs_in,
                const int* __restrict__ pairs_out,
                int* __restrict__ cursor,
                unsigned int* __restrict__ sorted, int P)
{
    int p = blockIdx.x * 256 + threadIdx.x;
    if (p < P) {
        size_t j = (size_t)blockIdx.y * P + p;
        int row = pairs_out[j];
        int in  = pairs_in[j];
        int slot = atomicAdd(&cursor[(row >> 6) * KSLOT + blockIdx.y], 1);
        sorted[slot] = ((unsigned)blockIdx.y << 23) | ((unsigned)in << 6)
                     | (unsigned)(row & 63);
    }
}

// W[k][kk][n] (f32) -> wbt[k][n][kk] (bf16) for direct B-fragment loads.
__global__ __launch_bounds__(256)
void k_wprep(const float* __restrict__ w, bf16_t* __restrict__ wbt, int total)
{
    int i = blockIdx.x * 256 + threadIdx.x;
    if (i < total) {
        int k  = i >> 12;
        int r  = i & 4095;
        int kk = r >> 6;
        int n  = r & 63;
        wbt[((size_t)k * 64 + n) * 64 + kk] = (bf16_t)w[i];
    }
}

// ------------------------- main: streamed groups, LDS-tile accumulation
__global__ __launch_bounds__(256)
void k_tile2(const float* __restrict__ features,
             const int* __restrict__ bstart,
             const unsigned int* __restrict__ sorted,
             const bf16_t* __restrict__ wbt,
             float* __restrict__ out,
             float* __restrict__ sums,
             int n_out, int n_buckets)
{
    __shared__ float ot[(R_TILE + 1) * OT_STRIDE];  // +1 trash row for pads
    __shared__ float red[128];

    const int tid  = threadIdx.x;
    const int wave = tid >> 6;
    const int lane = tid & 63;
    const int quad = lane >> 4;
    const int col  = lane & 15;

    const int t  = blockIdx.x;
    const int r0 = t * R_TILE;

    for (int i = tid; i < (R_TILE + 1) * OT_STRIDE; i += 256) ot[i] = 0.f;

    const int gbeg = bstart[t * KSLOT];
    const int gend = bstart[min((t + 1) * KSLOT, n_buckets)];
    const int ngroups = (gend - gbeg) >> 4;   // bucket sizes are 16-multiples

    __syncthreads();

    // Contiguous group ranges per wave -> same-k runs stay within a wave.
    const int chunk = (ngroups + 3) >> 2;
    const int g0 = wave * chunk;
    const int g1 = min(g0 + chunk, ngroups);

    int kprev = -1;
    bf16x8 bfrag[2][4];

    for (int g = g0; g < g1; ++g) {
        unsigned int val = sorted[gbeg + g * 16 + col];

        // Group is single-k; entry 0 (lane 0) is always real.
        int kg = (int)((__builtin_amdgcn_readfirstlane(val) >> 23) & 31);
        if (kg != kprev) {
            const bf16_t* wb = wbt + (size_t)kg * C_DIM * C_DIM;
            #pragma unroll
            for (int ks = 0; ks < 2; ++ks)
                #pragma unroll
                for (int nt = 0; nt < 4; ++nt)
                    bfrag[ks][nt] =
                        *(const bf16x8*)&wb[(col + 16 * nt) * C_DIM + quad * 8 + 32 * ks];
            kprev = kg;
        }

        bool pad   = (val == 0xFFFFFFFFu);
        int in_idx = pad ? 0 : (int)((val >> 6) & 0x1FFFF);

        const float* src = features + (size_t)in_idx * C_DIM + quad * 8;
        float4 f0 = *(const float4*)(src);
        float4 f1 = *(const float4*)(src + 4);
        float4 f2 = *(const float4*)(src + 32);
        float4 f3 = *(const float4*)(src + 36);

        bf16x8 a0, a1;
        a0[0] = (bf16_t)f0.x; a0[1] = (bf16_t)f0.y; a0[2] = (bf16_t)f0.z; a0[3] = (bf16_t)f0.w;
        a0[4] = (bf16_t)f1.x; a0[5] = (bf16_t)f1.y; a0[6] = (bf16_t)f1.z; a0[7] = (bf16_t)f1.w;
        a1[0] = (bf16_t)f2.x; a1[1] = (bf16_t)f2.y; a1[2] = (bf16_t)f2.z; a1[3] = (bf16_t)f2.w;
        a1[4] = (bf16_t)f3.x; a1[5] = (bf16_t)f3.y; a1[6] = (bf16_t)f3.z; a1[7] = (bf16_t)f3.w;

        floatx4 acc0 = {0.f, 0.f, 0.f, 0.f};
        floatx4 acc1 = {0.f, 0.f, 0.f, 0.f};
        floatx4 acc2 = {0.f, 0.f, 0.f, 0.f};
        floatx4 acc3 = {0.f, 0.f, 0.f, 0.f};

        acc0 = __builtin_amdgcn_mfma_f32_16x16x32_bf16(a0, bfrag[0][0], acc0, 0, 0, 0);
        acc0 = __builtin_amdgcn_mfma_f32_16x16x32_bf16(a1, bfrag[1][0], acc0, 0, 0, 0);
        acc1 = __builtin_amdgcn_mfma_f32_16x16x32_bf16(a0, bfrag[0][1], acc1, 0, 0, 0);
        acc1 = __builtin_amdgcn_mfma_f32_16x16x32_bf16(a1, bfrag[1][1], acc1, 0, 0, 0);
        acc2 = __builtin_amdgcn_mfma_f32_16x16x32_bf16(a0, bfrag[0][2], acc2, 0, 0, 0);
        acc2 = __builtin_amdgcn_mfma_f32_16x16x32_bf16(a1, bfrag[1][2], acc2, 0, 0, 0);
        acc3 = __builtin_amdgcn_mfma_f32_16x16x32_bf16(a0, bfrag[0][3], acc3, 0, 0, 0);
        acc3 = __builtin_amdgcn_mfma_f32_16x16x32_bf16(a1, bfrag[1][3], acc3, 0, 0, 0);

        // C/D: row m = quad*4+r, ch = col+16j. Pads land in trash row R_TILE.
        #pragma unroll
        for (int r = 0; r < 4; ++r) {
            int m = quad * 4 + r;
            unsigned int vm = __shfl(val, m);
            int lrow = (vm == 0xFFFFFFFFu) ? R_TILE : (int)(vm & 63);
            float* dst = &ot[lrow * OT_STRIDE + col];
            atomicAdd(dst +  0, acc0[r]);
            atomicAdd(dst + 16, acc1[r]);
            atomicAdd(dst + 32, acc2[r]);
            atomicAdd(dst + 48, acc3[r]);
        }
    }
    __syncthreads();

    // Write tile once (coalesced) + fused BN partial sums.
    float s[4]  = {0.f, 0.f, 0.f, 0.f};
    float s2[4] = {0.f, 0.f, 0.f, 0.f};
    for (int i = tid; i < R_TILE * 16; i += 256) {
        int rr = i >> 4, c4 = i & 15;
        int row = r0 + rr;
        if (row < n_out) {
            float4 v = *(const float4*)&ot[rr * OT_STRIDE + c4 * 4];
            *(float4*)&out[(size_t)row * C_DIM + c4 * 4] = v;
            s[0] += v.x; s2[0] += v.x * v.x;
            s[1] += v.y; s2[1] += v.y * v.y;
            s[2] += v.z; s2[2] += v.z * v.z;
            s[3] += v.w; s2[3] += v.w * v.w;
        }
    }
    if (tid < 128) red[tid] = 0.f;
    __syncthreads();
    {
        int c4 = tid & 15;
        #pragma unroll
        for (int j = 0; j < 4; ++j) {
            atomicAdd(&red[c4 * 4 + j], s[j]);
            atomicAdd(&red[64 + c4 * 4 + j], s2[j]);
        }
    }
    __syncthreads();
    if (tid < 128) atomicAdd(&sums[tid], red[tid]);
}

// --------------------------------------------------- BN normalize + ReLU
__global__ __launch_bounds__(256)
void k3_bn_relu(float* __restrict__ out, const float* __restrict__ sums,
                const float* __restrict__ gamma, const float* __restrict__ beta,
                int n_rows)
{
    int tid = blockIdx.x * 256 + threadIdx.x;
    int ch0 = (tid * 4) & 63;
    float inv_n = 1.0f / (float)n_rows;

    float sc[4], sh[4];
    #pragma unroll
    for (int j = 0; j < 4; ++j) {
        int ch    = ch0 + j;
        float m   = sums[ch] * inv_n;
        float var = sums[64 + ch] * inv_n - m * m;
        float inv = rsqrtf(var + 1e-5f);
        float g   = gamma[ch] * inv;
        sc[j] = g;
        sh[j] = beta[ch] - m * g;
    }

    size_t total = (size_t)n_rows * C_DIM / 4;
    for (size_t i = tid; i < total; i += (size_t)gridDim.x * 256) {
        float4 v = ((const float4*)out)[i];
        v.x = fmaxf(v.x * sc[0] + sh[0], 0.f);
        v.y = fmaxf(v.y * sc[1] + sh[1], 0.f);
        v.z = fmaxf(v.z * sc[2] + sh[2], 0.f);
        v.w = fmaxf(v.w * sc[3] + sh[3], 0.f);
        ((float4*)out)[i] = v;
    }
}

// ===================== fallback (R1 atomic path, known-good) ================
__global__ __launch_bounds__(256)
void k1_scatter_gemm(const float* __restrict__ features,
                     const float* __restrict__ weight,
                     const int* __restrict__ pairs_in,
                     const int* __restrict__ pairs_out,
                     float* __restrict__ out,
                     int P, int rows_per_block)
{
    __shared__ bf16_t Wt[C_DIM * LDS_STRIDE];
    const int k   = blockIdx.y;
    const int tid = threadIdx.x;
    const float* Wk = weight + (size_t)k * C_DIM * C_DIM;
    for (int i = tid; i < C_DIM * C_DIM; i += 256) {
        int c = i >> 6, d = i & 63;
        Wt[d * LDS_STRIDE + c] = (bf16_t)Wk[i];
    }
    __syncthreads();
    const int wave = tid >> 6, lane = tid & 63, quad = lane >> 4, col = lane & 15;
    bf16x8 bfrag[2][4];
    #pragma unroll
    for (int ks = 0; ks < 2; ++ks)
        #pragma unroll
        for (int nt = 0; nt < 4; ++nt)
            bfrag[ks][nt] =
                *(const bf16x8*)&Wt[(col + 16 * nt) * LDS_STRIDE + quad * 8 + 32 * ks];
    const int* __restrict__ pin  = pairs_in  + (size_t)k * P;
    const int* __restrict__ pout = pairs_out + (size_t)k * P;
    const int p0   = blockIdx.x * rows_per_block;
    const int pend = min(p0 + rows_per_block, P);
    for (int base = p0 + wave * 16; base < pend; base += 64) {
        int prow    = base + col;
        int clamped = (prow < pend) ? prow : (pend - 1);
        int in_idx  = pin[clamped];
        int out_idx = pout[clamped];
        const float* src = features + (size_t)in_idx * C_DIM + quad * 8;
        float4 f0 = *(const float4*)(src);
        float4 f1 = *(const float4*)(src + 4);
        float4 f2 = *(const float4*)(src + 32);
        float4 f3 = *(const float4*)(src + 36);
        bf16x8 a0, a1;
        a0[0] = (bf16_t)f0.x; a0[1] = (bf16_t)f0.y; a0[2] = (bf16_t)f0.z; a0[3] = (bf16_t)f0.w;
        a0[4] = (bf16_t)f1.x; a0[5] = (bf16_t)f1.y; a0[6] = (bf16_t)f1.z; a0[7] = (bf16_t)f1.w;
        a1[0] = (bf16_t)f2.x; a1[1] = (bf16_t)f2.y; a1[2] = (bf16_t)f2.z; a1[3] = (bf16_t)f2.w;
        a1[4] = (bf16_t)f3.x; a1[5] = (bf16_t)f3.y; a1[6] = (bf16_t)f3.z; a1[7] = (bf16_t)f3.w;
        floatx4 acc0 = {0.f,0.f,0.f,0.f}, acc1 = {0.f,0.f,0.f,0.f};
        floatx4 acc2 = {0.f,0.f,0.f,0.f}, acc3 = {0.f,0.f,0.f,0.f};
        acc0 = __builtin_amdgcn_mfma_f32_16x16x32_bf16(a0, bfrag[0][0], acc0, 0, 0, 0);
        acc0 = __builtin_amdgcn_mfma_f32_16x16x32_bf16(a1, bfrag[1][0], acc0, 0, 0, 0);
        acc1 = __builtin_amdgcn_mfma_f32_16x16x32_bf16(a0, bfrag[0][1], acc1, 0, 0, 0);
        acc1 = __builtin_amdgcn_mfma_f32_16x16x32_bf16(a1, bfrag[1][1], acc1, 0, 0, 0);
        acc2 = __builtin_amdgcn_mfma_f32_16x16x32_bf16(a0, bfrag[0][2], acc2, 0, 0, 0);
        acc2 = __builtin_amdgcn_mfma_f32_16x16x32_bf16(a1, bfrag[1][2], acc2, 0, 0, 0);
        acc3 = __builtin_amdgcn_mfma_f32_16x16x32_bf16(a0, bfrag[0][3], acc3, 0, 0, 0);
        acc3 = __builtin_amdgcn_mfma_f32_16x16x32_bf16(a1, bfrag[1][3], acc3, 0, 0, 0);
        #pragma unroll
        for (int r = 0; r < 4; ++r) {
            int m = quad * 4 + r;
            int g = __shfl(out_idx, m);
            if (base + m < pend) {
                float* dst = out + (size_t)g * C_DIM + col;
                unsafeAtomicAdd(dst +  0, acc0[r]);
                unsafeAtomicAdd(dst + 16, acc1[r]);
                unsafeAtomicAdd(dst + 32, acc2[r]);
                unsafeAtomicAdd(dst + 48, acc3[r]);
            }
        }
    }
}

__global__ __launch_bounds__(256)
void k2_stats(const float* __restrict__ acc, float* __restrict__ sums, int n_rows)
{
    int tid = threadIdx.x;
    int ch  = tid & 63;
    int sub = tid >> 6;
    float s = 0.f, s2 = 0.f;
    for (int r = blockIdx.x * 4 + sub; r < n_rows; r += gridDim.x * 4) {
        float v = acc[(size_t)r * C_DIM + ch];
        s  += v;
        s2 += v * v;
    }
    __shared__ float red[256];
    red[tid] = s;
    __syncthreads();
    if (tid < 64) {
        float t = red[tid] + red[tid + 64] + red[tid + 128] + red[tid + 192];
        atomicAdd(&sums[ch], t);
    }
    __syncthreads();
    red[tid] = s2;
    __syncthreads();
    if (tid < 64) {
        float t = red[tid] + red[tid + 64] + red[tid + 128] + red[tid + 192];
        atomicAdd(&sums[64 + ch], t);
    }
}

// ============================================================================
extern "C" void kernel_launch(void* const* d_in, const int* in_sizes, int n_in,
                              void* d_out, int out_size, void* d_ws, size_t ws_size,
                              hipStream_t stream)
{
    const float* features  = (const float*)d_in[0];
    const float* weight    = (const float*)d_in[1];
    // d_in[2] = bias (cancels in training-mode BN)
    const float* gamma     = (const float*)d_in[3];
    const float* beta      = (const float*)d_in[4];
    const int*   pairs_in  = (const int*)d_in[5];
    const int*   pairs_out = (const int*)d_in[6];

    const int n_out = out_size / C_DIM;
    const int n_in_rows = in_sizes[0] / C_DIM;
    const int K3    = in_sizes[1] / (C_DIM * C_DIM);
    const int P     = in_sizes[5] / K3;
    const int M     = in_sizes[5];

    const int ntiles    = (n_out + R_TILE - 1) / R_TILE;
    const int n_buckets = ntiles * KSLOT;
    const int nb        = (n_buckets + 1023) / 1024;
    const size_t m_pad_max = (size_t)M + (size_t)n_buckets * 15;

    float* out = (float*)d_out;

    // ws layout (bytes)
    size_t off_sums = 0;                                        // 128 f32
    size_t off_bs   = 512;                                      // n_buckets+1
    size_t off_cur  = off_bs  + (size_t)(n_buckets + 1) * 4;    // n_buckets
    size_t off_part = off_cur + (size_t)n_buckets * 4;          // nb
    size_t off_wbt  = (off_part + (size_t)nb * 4 + 255) & ~(size_t)255;
    size_t off_srt  = (off_wbt + (size_t)K3 * C_DIM * C_DIM * 2 + 255) & ~(size_t)255;
    size_t need     = off_srt + m_pad_max * 4;

    float*        sums    = (float*)((char*)d_ws + off_sums);
    int*          bstart  = (int*)((char*)d_ws + off_bs);
    int*          cursor  = (int*)((char*)d_ws + off_cur);
    int*          partials= (int*)((char*)d_ws + off_part);
    bf16_t*       wbt     = (bf16_t*)((char*)d_ws + off_wbt);
    unsigned int* sorted  = (unsigned int*)((char*)d_ws + off_srt);

    if (ws_size >= need && nb <= 1024 && K3 <= 32 && n_in_rows <= (1 << 17)) {
        hipMemsetAsync(sums, 0, 512, stream);
        hipMemsetAsync(cursor, 0, (size_t)n_buckets * 4, stream);
        hipMemsetAsync(sorted, 0xFF, m_pad_max * 4, stream);

        dim3 gp((P + 255) / 256, K3);
        k_hist2<<<gp, 256, 0, stream>>>(pairs_out, cursor, P);
        k_scan_a<<<nb, 256, 0, stream>>>(cursor, partials, n_buckets);
        k_scan_b<<<1, 1024, 0, stream>>>(partials, nb);
        k_scan_c<<<nb, 256, 0, stream>>>(cursor, bstart, partials, n_buckets);
        k_scatter2<<<gp, 256, 0, stream>>>(pairs_in, pairs_out, cursor, sorted, P);
        k_wprep<<<(K3 * 4096 + 255) / 256, 256, 0, stream>>>(weight, wbt, K3 * 4096);

        k_tile2<<<ntiles, 256, 0, stream>>>(features, bstart, sorted, wbt,
                                            out, sums, n_out, n_buckets);

        k3_bn_relu<<<dim3(1024), 256, 0, stream>>>(out, sums, gamma, beta, n_out);
    } else {
        // fallback: R1 atomic-scatter path (proven, 592us)
        hipMemsetAsync(d_out, 0, (size_t)out_size * sizeof(float), stream);
        hipMemsetAsync(d_ws, 0, 512, stream);

        const int rows_per_block = 512;
        dim3 g1((P + rows_per_block - 1) / rows_per_block, K3);
        k1_scatter_gemm<<<g1, 256, 0, stream>>>(features, weight, pairs_in,
                                                pairs_out, out, P, rows_per_block);
        k2_stats<<<dim3(1024), 256, 0, stream>>>(out, sums, n_out);
        k3_bn_relu<<<dim3(1024), 256, 0, stream>>>(out, sums, gamma, beta, n_out);
    }
}

// Round 6
// 367.090 us; speedup vs baseline: 3.8666x; 3.5794x over previous
//
#include <hip/hip_runtime.h>
#include <hip/hip_fp16.h>

// SparseConvTransposeBlock, round 6: R1 streaming structure + halved atomic
// payload.
//
// Evidence: R1 (stream pairs, global fp32 atomics) = 447us, limited by the
// atomic write-through drain (540MB, 4 lines/row). R3 (256B contiguous
// atomics) = identical -> bound by bytes/lines, not segments. R4/R5
// (tile-ownership, zero atomics) = ~1000us, latency-collapsed. So: keep R1,
// shrink the payload. (1) fp16 packed atomics (global_atomic_pk_add_f16)
// into a ws accumulator: 540->270MB, 4->2 lines/row. (2) bf16 feature table
// prepass: gather fetch 240->~130MB. Expected absmax ~0.05 (thr 0.1275).
//
// Bias cancels in training-mode BN: y = (acc - mean_acc)*rsqrt(var)*g + b.

#define C_DIM 64
#define LDS_STRIDE 72   // bf16 elems per Wt row: 64 + 8 pad
#define ROW_STRIDE 68   // fp32 elems per scratch row: 64 + 4 pad

typedef __bf16 bf16_t;
typedef bf16_t bf16x4 __attribute__((ext_vector_type(4)));
typedef bf16_t bf16x8 __attribute__((ext_vector_type(8)));
typedef float floatx4 __attribute__((ext_vector_type(4)));

// ---------------------------------------------- features f32 -> bf16 table
__global__ __launch_bounds__(256)
void k_fprep(const float* __restrict__ f, bf16_t* __restrict__ fb, int total4)
{
    int i = blockIdx.x * 256 + threadIdx.x;
    if (i < total4) {
        float4 v = ((const float4*)f)[i];
        bf16x4 o;
        o[0] = (bf16_t)v.x; o[1] = (bf16_t)v.y;
        o[2] = (bf16_t)v.z; o[3] = (bf16_t)v.w;
        ((bf16x4*)fb)[i] = o;
    }
}

// ------------------- main: stream pairs, MFMA, fp16 packed atomic scatter
__global__ __launch_bounds__(256)
void k1_fp16(const float* __restrict__ features,
             const bf16_t* __restrict__ fbf16,
             const float* __restrict__ weight,
             const int* __restrict__ pairs_in,
             const int* __restrict__ pairs_out,
             __half* __restrict__ acc,
             int P, int rows_per_block, int use_bf16)
{
    __shared__ bf16_t Wt[C_DIM * LDS_STRIDE];
    __shared__ float  scratch[4][16 * ROW_STRIDE];

    const int k   = blockIdx.y;
    const int tid = threadIdx.x;

    // Stage W_k^T into LDS as bf16: Wt[d][c] = W[k][c][d].
    const float* Wk = weight + (size_t)k * C_DIM * C_DIM;
    for (int i = tid; i < C_DIM * C_DIM; i += 256) {
        int c = i >> 6, d = i & 63;
        Wt[d * LDS_STRIDE + c] = (bf16_t)Wk[i];
    }
    __syncthreads();

    const int wave = tid >> 6;
    const int lane = tid & 63;
    const int quad = lane >> 4;
    const int col  = lane & 15;
    const int sub  = lane >> 5;   // 0/1: which of 2 rows in the pk-atomic loop
    const int c2   = lane & 31;   // half2 column index
    float* ls = &scratch[wave][0];

    // B fragments: lane holds B[kk = quad*8+j+32*ks][n = col+16*nt] = Wt[n][kk].
    bf16x8 bfrag[2][4];
    #pragma unroll
    for (int ks = 0; ks < 2; ++ks)
        #pragma unroll
        for (int nt = 0; nt < 4; ++nt)
            bfrag[ks][nt] =
                *(const bf16x8*)&Wt[(col + 16 * nt) * LDS_STRIDE + quad * 8 + 32 * ks];

    const int* __restrict__ pin  = pairs_in  + (size_t)k * P;
    const int* __restrict__ pout = pairs_out + (size_t)k * P;

    const int p0   = blockIdx.x * rows_per_block;
    const int pend = min(p0 + rows_per_block, P);

    for (int base = p0 + wave * 16; base < pend; base += 64) {
        int prow    = base + col;
        int clamped = (prow < pend) ? prow : (pend - 1);
        int in_idx  = pin[clamped];
        int out_idx = pout[clamped];   // lanes 0..15 hold rows base..base+15

        // Gather A fragments in MFMA A-layout:
        // A[m = col][kk = quad*8 + j + 32*ks] = features[in_idx][kk].
        bf16x8 a0, a1;
        if (use_bf16) {
            const bf16_t* src = fbf16 + (size_t)in_idx * C_DIM + quad * 8;
            a0 = *(const bf16x8*)(src);
            a1 = *(const bf16x8*)(src + 32);
        } else {
            const float* src = features + (size_t)in_idx * C_DIM + quad * 8;
            float4 f0 = *(const float4*)(src);
            float4 f1 = *(const float4*)(src + 4);
            float4 f2 = *(const float4*)(src + 32);
            float4 f3 = *(const float4*)(src + 36);
            a0[0] = (bf16_t)f0.x; a0[1] = (bf16_t)f0.y; a0[2] = (bf16_t)f0.z; a0[3] = (bf16_t)f0.w;
            a0[4] = (bf16_t)f1.x; a0[5] = (bf16_t)f1.y; a0[6] = (bf16_t)f1.z; a0[7] = (bf16_t)f1.w;
            a1[0] = (bf16_t)f2.x; a1[1] = (bf16_t)f2.y; a1[2] = (bf16_t)f2.z; a1[3] = (bf16_t)f2.w;
            a1[4] = (bf16_t)f3.x; a1[5] = (bf16_t)f3.y; a1[6] = (bf16_t)f3.z; a1[7] = (bf16_t)f3.w;
        }

        floatx4 acc0 = {0.f, 0.f, 0.f, 0.f};
        floatx4 acc1 = {0.f, 0.f, 0.f, 0.f};
        floatx4 acc2 = {0.f, 0.f, 0.f, 0.f};
        floatx4 acc3 = {0.f, 0.f, 0.f, 0.f};

        acc0 = __builtin_amdgcn_mfma_f32_16x16x32_bf16(a0, bfrag[0][0], acc0, 0, 0, 0);
        acc0 = __builtin_amdgcn_mfma_f32_16x16x32_bf16(a1, bfrag[1][0], acc0, 0, 0, 0);
        acc1 = __builtin_amdgcn_mfma_f32_16x16x32_bf16(a0, bfrag[0][1], acc1, 0, 0, 0);
        acc1 = __builtin_amdgcn_mfma_f32_16x16x32_bf16(a1, bfrag[1][1], acc1, 0, 0, 0);
        acc2 = __builtin_amdgcn_mfma_f32_16x16x32_bf16(a0, bfrag[0][2], acc2, 0, 0, 0);
        acc2 = __builtin_amdgcn_mfma_f32_16x16x32_bf16(a1, bfrag[1][2], acc2, 0, 0, 0);
        acc3 = __builtin_amdgcn_mfma_f32_16x16x32_bf16(a0, bfrag[0][3], acc3, 0, 0, 0);
        acc3 = __builtin_amdgcn_mfma_f32_16x16x32_bf16(a1, bfrag[1][3], acc3, 0, 0, 0);

        // Repack C tile into per-wave LDS (R3 pattern, measured-neutral):
        // ls[m][ch], m = quad*4 + r, ch = col + 16j.
        #pragma unroll
        for (int r = 0; r < 4; ++r) {
            int m = quad * 4 + r;
            ls[m * ROW_STRIDE + col +  0] = acc0[r];
            ls[m * ROW_STRIDE + col + 16] = acc1[r];
            ls[m * ROW_STRIDE + col + 32] = acc2[r];
            ls[m * ROW_STRIDE + col + 48] = acc3[r];
        }
        // Wave-private scratch: drain LDS only (keep global atomics in flight).
        asm volatile("s_waitcnt lgkmcnt(0)" ::: "memory");

        // fp16 packed atomics: 2 rows per instruction, 32 half2 per row.
        // Per row: 128B = 2 cache lines (vs 4 for fp32).
        #pragma unroll
        for (int m2 = 0; m2 < 8; ++m2) {
            int m = m2 * 2 + sub;
            float2 v = *(const float2*)&ls[m * ROW_STRIDE + 2 * c2];
            __half2 h = __floats2half2_rn(v.x, v.y);
            int g = __shfl(out_idx, m);
            if (base + m < pend)
                unsafeAtomicAdd((__half2*)(acc + (size_t)g * C_DIM + 2 * c2), h);
        }
    }
}

// ---------------------- per-channel sum / sumsq over the fp16 accumulator
__global__ __launch_bounds__(256)
void k2_stats_h(const __half* __restrict__ acc, float* __restrict__ sums,
                int n_rows)
{
    const int tid = threadIdx.x;
    const int c2  = tid & 31;   // half2 column
    const int sub = tid >> 5;   // 8 rows per block pass

    float s0 = 0.f, s1 = 0.f, q0 = 0.f, q1 = 0.f;
    for (int r = blockIdx.x * 8 + sub; r < n_rows; r += gridDim.x * 8) {
        __half2 v = *(const __half2*)&acc[(size_t)r * C_DIM + 2 * c2];
        float x = __half2float(v.x), y = __half2float(v.y);
        s0 += x; q0 += x * x;
        s1 += y; q1 += y * y;
    }

    __shared__ float red[128];
    if (tid < 128) red[tid] = 0.f;
    __syncthreads();
    atomicAdd(&red[2 * c2], s0);
    atomicAdd(&red[2 * c2 + 1], s1);
    atomicAdd(&red[64 + 2 * c2], q0);
    atomicAdd(&red[64 + 2 * c2 + 1], q1);
    __syncthreads();
    if (tid < 128) atomicAdd(&sums[tid], red[tid]);
}

// ------------------------- BN normalize + ReLU: fp16 acc -> fp32 out
__global__ __launch_bounds__(256)
void k3_bn_relu_h(const __half* __restrict__ acc, float* __restrict__ out,
                  const float* __restrict__ sums,
                  const float* __restrict__ gamma, const float* __restrict__ beta,
                  int n_rows)
{
    int tid = blockIdx.x * 256 + threadIdx.x;
    int c2  = tid & 31;                  // fixed half2 column per thread
    float inv_n = 1.0f / (float)n_rows;

    float sc[2], sh[2];
    #pragma unroll
    for (int j = 0; j < 2; ++j) {
        int ch    = 2 * c2 + j;
        float m   = sums[ch] * inv_n;
        float var = sums[64 + ch] * inv_n - m * m;
        float inv = rsqrtf(var + 1e-5f);
        float g   = gamma[ch] * inv;
        sc[j] = g;
        sh[j] = beta[ch] - m * g;
    }

    size_t total = (size_t)n_rows * (C_DIM / 2);
    for (size_t i = tid; i < total; i += (size_t)gridDim.x * 256) {
        __half2 v = ((const __half2*)acc)[i];
        float2 o;
        o.x = fmaxf(__half2float(v.x) * sc[0] + sh[0], 0.f);
        o.y = fmaxf(__half2float(v.y) * sc[1] + sh[1], 0.f);
        ((float2*)out)[i] = o;
    }
}

// ===================== fallback (R1 path, proven 592us total) ===============
__global__ __launch_bounds__(256)
void k1_scatter_gemm(const float* __restrict__ features,
                     const float* __restrict__ weight,
                     const int* __restrict__ pairs_in,
                     const int* __restrict__ pairs_out,
                     float* __restrict__ out,
                     int P, int rows_per_block)
{
    __shared__ bf16_t Wt[C_DIM * LDS_STRIDE];
    const int k   = blockIdx.y;
    const int tid = threadIdx.x;
    const float* Wk = weight + (size_t)k * C_DIM * C_DIM;
    for (int i = tid; i < C_DIM * C_DIM; i += 256) {
        int c = i >> 6, d = i & 63;
        Wt[d * LDS_STRIDE + c] = (bf16_t)Wk[i];
    }
    __syncthreads();
    const int wave = tid >> 6, lane = tid & 63, quad = lane >> 4, col = lane & 15;
    bf16x8 bfrag[2][4];
    #pragma unroll
    for (int ks = 0; ks < 2; ++ks)
        #pragma unroll
        for (int nt = 0; nt < 4; ++nt)
            bfrag[ks][nt] =
                *(const bf16x8*)&Wt[(col + 16 * nt) * LDS_STRIDE + quad * 8 + 32 * ks];
    const int* __restrict__ pin  = pairs_in  + (size_t)k * P;
    const int* __restrict__ pout = pairs_out + (size_t)k * P;
    const int p0   = blockIdx.x * rows_per_block;
    const int pend = min(p0 + rows_per_block, P);
    for (int base = p0 + wave * 16; base < pend; base += 64) {
        int prow    = base + col;
        int clamped = (prow < pend) ? prow : (pend - 1);
        int in_idx  = pin[clamped];
        int out_idx = pout[clamped];
        const float* src = features + (size_t)in_idx * C_DIM + quad * 8;
        float4 f0 = *(const float4*)(src);
        float4 f1 = *(const float4*)(src + 4);
        float4 f2 = *(const float4*)(src + 32);
        float4 f3 = *(const float4*)(src + 36);
        bf16x8 a0, a1;
        a0[0] = (bf16_t)f0.x; a0[1] = (bf16_t)f0.y; a0[2] = (bf16_t)f0.z; a0[3] = (bf16_t)f0.w;
        a0[4] = (bf16_t)f1.x; a0[5] = (bf16_t)f1.y; a0[6] = (bf16_t)f1.z; a0[7] = (bf16_t)f1.w;
        a1[0] = (bf16_t)f2.x; a1[1] = (bf16_t)f2.y; a1[2] = (bf16_t)f2.z; a1[3] = (bf16_t)f2.w;
        a1[4] = (bf16_t)f3.x; a1[5] = (bf16_t)f3.y; a1[6] = (bf16_t)f3.z; a1[7] = (bf16_t)f3.w;
        floatx4 acc0 = {0.f,0.f,0.f,0.f}, acc1 = {0.f,0.f,0.f,0.f};
        floatx4 acc2 = {0.f,0.f,0.f,0.f}, acc3 = {0.f,0.f,0.f,0.f};
        acc0 = __builtin_amdgcn_mfma_f32_16x16x32_bf16(a0, bfrag[0][0], acc0, 0, 0, 0);
        acc0 = __builtin_amdgcn_mfma_f32_16x16x32_bf16(a1, bfrag[1][0], acc0, 0, 0, 0);
        acc1 = __builtin_amdgcn_mfma_f32_16x16x32_bf16(a0, bfrag[0][1], acc1, 0, 0, 0);
        acc1 = __builtin_amdgcn_mfma_f32_16x16x32_bf16(a1, bfrag[1][1], acc1, 0, 0, 0);
        acc2 = __builtin_amdgcn_mfma_f32_16x16x32_bf16(a0, bfrag[0][2], acc2, 0, 0, 0);
        acc2 = __builtin_amdgcn_mfma_f32_16x16x32_bf16(a1, bfrag[1][2], acc2, 0, 0, 0);
        acc3 = __builtin_amdgcn_mfma_f32_16x16x32_bf16(a0, bfrag[0][3], acc3, 0, 0, 0);
        acc3 = __builtin_amdgcn_mfma_f32_16x16x32_bf16(a1, bfrag[1][3], acc3, 0, 0, 0);
        #pragma unroll
        for (int r = 0; r < 4; ++r) {
            int m = quad * 4 + r;
            int g = __shfl(out_idx, m);
            if (base + m < pend) {
                float* dst = out + (size_t)g * C_DIM + col;
                unsafeAtomicAdd(dst +  0, acc0[r]);
                unsafeAtomicAdd(dst + 16, acc1[r]);
                unsafeAtomicAdd(dst + 32, acc2[r]);
                unsafeAtomicAdd(dst + 48, acc3[r]);
            }
        }
    }
}

__global__ __launch_bounds__(256)
void k2_stats(const float* __restrict__ acc, float* __restrict__ sums, int n_rows)
{
    int tid = threadIdx.x;
    int ch  = tid & 63;
    int sub = tid >> 6;
    float s = 0.f, s2 = 0.f;
    for (int r = blockIdx.x * 4 + sub; r < n_rows; r += gridDim.x * 4) {
        float v = acc[(size_t)r * C_DIM + ch];
        s  += v;
        s2 += v * v;
    }
    __shared__ float red[256];
    red[tid] = s;
    __syncthreads();
    if (tid < 64) {
        float t = red[tid] + red[tid + 64] + red[tid + 128] + red[tid + 192];
        atomicAdd(&sums[ch], t);
    }
    __syncthreads();
    red[tid] = s2;
    __syncthreads();
    if (tid < 64) {
        float t = red[tid] + red[tid + 64] + red[tid + 128] + red[tid + 192];
        atomicAdd(&sums[64 + ch], t);
    }
}

__global__ __launch_bounds__(256)
void k3_bn_relu(float* __restrict__ out, const float* __restrict__ sums,
                const float* __restrict__ gamma, const float* __restrict__ beta,
                int n_rows)
{
    int tid = blockIdx.x * 256 + threadIdx.x;
    int ch0 = (tid * 4) & 63;
    float inv_n = 1.0f / (float)n_rows;
    float sc[4], sh[4];
    #pragma unroll
    for (int j = 0; j < 4; ++j) {
        int ch    = ch0 + j;
        float m   = sums[ch] * inv_n;
        float var = sums[64 + ch] * inv_n - m * m;
        float inv = rsqrtf(var + 1e-5f);
        float g   = gamma[ch] * inv;
        sc[j] = g;
        sh[j] = beta[ch] - m * g;
    }
    size_t total = (size_t)n_rows * C_DIM / 4;
    for (size_t i = tid; i < total; i += (size_t)gridDim.x * 256) {
        float4 v = ((const float4*)out)[i];
        v.x = fmaxf(v.x * sc[0] + sh[0], 0.f);
        v.y = fmaxf(v.y * sc[1] + sh[1], 0.f);
        v.z = fmaxf(v.z * sc[2] + sh[2], 0.f);
        v.w = fmaxf(v.w * sc[3] + sh[3], 0.f);
        ((float4*)out)[i] = v;
    }
}

// ============================================================================
extern "C" void kernel_launch(void* const* d_in, const int* in_sizes, int n_in,
                              void* d_out, int out_size, void* d_ws, size_t ws_size,
                              hipStream_t stream)
{
    const float* features  = (const float*)d_in[0];
    const float* weight    = (const float*)d_in[1];
    // d_in[2] = bias (cancels in training-mode BN)
    const float* gamma     = (const float*)d_in[3];
    const float* beta      = (const float*)d_in[4];
    const int*   pairs_in  = (const int*)d_in[5];
    const int*   pairs_out = (const int*)d_in[6];

    const int n_out     = out_size / C_DIM;
    const int n_in_rows = in_sizes[0] / C_DIM;
    const int K3        = in_sizes[1] / (C_DIM * C_DIM);
    const int P         = in_sizes[5] / K3;

    float* out = (float*)d_out;

    // ws layout: sums(512B) | fp16 acc | bf16 features
    size_t acc_bytes = (size_t)n_out * C_DIM * 2;
    size_t off_acc   = 512;
    size_t off_fb    = (off_acc + acc_bytes + 255) & ~(size_t)255;
    size_t fb_bytes  = (size_t)n_in_rows * C_DIM * 2;
    size_t need_b    = off_acc + acc_bytes;
    size_t need_a    = off_fb + fb_bytes;

    float*  sums  = (float*)d_ws;
    __half* acc   = (__half*)((char*)d_ws + off_acc);
    bf16_t* fbf16 = (bf16_t*)((char*)d_ws + off_fb);

    const int rows_per_block = 512;
    dim3 g1((P + rows_per_block - 1) / rows_per_block, K3);

    if (ws_size >= need_b) {
        const int use_bf16 = (ws_size >= need_a) ? 1 : 0;

        hipMemsetAsync(sums, 0, 512, stream);
        hipMemsetAsync(acc, 0, acc_bytes, stream);
        if (use_bf16)
            k_fprep<<<(n_in_rows * 16 + 255) / 256, 256, 0, stream>>>(
                features, fbf16, n_in_rows * 16);

        k1_fp16<<<g1, 256, 0, stream>>>(features, fbf16, weight, pairs_in,
                                        pairs_out, acc, P, rows_per_block,
                                        use_bf16);

        k2_stats_h<<<dim3(1024), 256, 0, stream>>>(acc, sums, n_out);
        k3_bn_relu_h<<<dim3(1024), 256, 0, stream>>>(acc, out, sums, gamma,
                                                     beta, n_out);
    } else {
        // fallback: proven R1 path
        hipMemsetAsync(d_out, 0, (size_t)out_size * sizeof(float), stream);
        hipMemsetAsync(d_ws, 0, 512, stream);

        k1_scatter_gemm<<<g1, 256, 0, stream>>>(features, weight, pairs_in,
                                                pairs_out, out, P, rows_per_block);
        k2_stats<<<dim3(1024), 256, 0, stream>>>(out, sums, n_out);
        k3_bn_relu<<<dim3(1024), 256, 0, stream>>>(out, sums, gamma, beta, n_out);
    }
}